// Round 2
// baseline (5184.255 us; speedup 1.0000x reference)
//
#include <hip/hip_runtime.h>
#include <stdint.h>

#define BN_ 8192
#define DN_ 1024
#define INV_T 10.0f
#define SHIFT_ 460.0f

typedef __attribute__((ext_vector_type(8))) short bf16x8;
typedef __attribute__((ext_vector_type(4))) float f32x4;

__device__ __forceinline__ float bf2f(unsigned short u) {
  return __uint_as_float(((unsigned int)u) << 16);
}
__device__ __forceinline__ unsigned short f2bf(float f) {
  unsigned int u = __float_as_uint(f);
  return (unsigned short)((u + 0x7FFFu + ((u >> 16) & 1u)) >> 16);
}

// ---------------- prep: fp32 -> bf16 cast + row sum-of-squares ----------------
__global__ void prep_kernel(const float* __restrict__ gen, const float* __restrict__ pos,
                            unsigned short* __restrict__ gen_h, unsigned short* __restrict__ pos_h,
                            float* __restrict__ gn2, float* __restrict__ pn2) {
  int b = blockIdx.x;
  const float* src; unsigned short* dst; float* n2; int row;
  if (b < BN_) { src = gen; dst = gen_h; n2 = gn2; row = b; }
  else         { src = pos; dst = pos_h; n2 = pn2; row = b - BN_; }
  int t = threadIdx.x;
  float4 v = ((const float4*)(src + (size_t)row * DN_))[t];
  float ss = v.x * v.x + v.y * v.y + v.z * v.z + v.w * v.w;
  ushort4 o;
  o.x = f2bf(v.x); o.y = f2bf(v.y); o.z = f2bf(v.z); o.w = f2bf(v.w);
  ((ushort4*)(dst + (size_t)row * DN_))[t] = o;
#pragma unroll
  for (int m = 1; m < 64; m <<= 1) ss += __shfl_xor(ss, m);
  __shared__ float red[4];
  if ((t & 63) == 0) red[t >> 6] = ss;
  __syncthreads();
  if (t == 0) n2[row] = red[0] + red[1] + red[2] + red[3];
}

// ---------------- transpose: fp32 [8192][1024] -> bf16 [1024][8192] ----------------
__global__ void transpose_kernel(const float* __restrict__ gen, const float* __restrict__ pos,
                                 unsigned short* __restrict__ genT, unsigned short* __restrict__ posT) {
  __shared__ float tile[64][65];
  int b = blockIdx.x;
  const float* src; unsigned short* dst;
  if (b < 2048) { src = gen; dst = genT; }
  else          { src = pos; dst = posT; b -= 2048; }
  int tj = b >> 4, td = b & 15;
  int t = threadIdx.x;
#pragma unroll
  for (int it = 0; it < 16; ++it) {
    int idx = it * 256 + t;
    int r = idx >> 6, c = idx & 63;
    tile[r][c] = src[(size_t)(tj * 64 + r) * DN_ + td * 64 + c];
  }
  __syncthreads();
#pragma unroll
  for (int it = 0; it < 16; ++it) {
    int idx = it * 256 + t;
    int d = idx >> 6, j = idx & 63;
    dst[(size_t)(td * 64 + d) * BN_ + tj * 64 + j] = f2bf(tile[j][d]);
  }
}

// ---------------- flash kernel ----------------
// mode 0: attraction  (K/V = pos), writes attr buffer, gs[2] += sum||attr_i||
// mode 1: repulsion concurrent (K/V = gen, diag mask), writes rep buffer, gs[3]
// mode 2: repulsion standalone (reads attr inline, full drift stats) -- fallback path
// mode_sel = -1: concurrent dispatch, blockIdx<256 -> mode0, else mode1.
__launch_bounds__(256, 2)
__global__ void flash_kernel(const unsigned short* __restrict__ gen_h,
                             const unsigned short* __restrict__ pos_h,
                             const unsigned short* __restrict__ genT,
                             const unsigned short* __restrict__ posT,
                             const float* __restrict__ gn2,
                             const float* __restrict__ pn2,
                             const float* __restrict__ genf,
                             unsigned short* __restrict__ attr,
                             unsigned short* __restrict__ rep,
                             float* __restrict__ gs,
                             int mode_sel) {
  __shared__ __align__(16) unsigned short Ks[64][264];  // 64 j x 256 d chunk (+8 pad = 16B)
  __shared__ __align__(16) unsigned short Ps[32][72];   // P tile: 32 i x 64 j (+8 pad)
  __shared__ float kn2s[64];
  __shared__ float qn2s[32];
  __shared__ float larr[32];
  __shared__ float rsqA[32];
  __shared__ float rsqB[32];

  int mode, ib;
  if (mode_sel < 0) { ib = blockIdx.x & 255; mode = blockIdx.x >> 8; }
  else { ib = blockIdx.x; mode = mode_sel; }

  const unsigned short* Kh; const unsigned short* VT; const float* kn2p;
  unsigned short* outp; bool mask;
  if (mode == 0) { Kh = pos_h; VT = posT; kn2p = pn2; outp = attr; mask = false; }
  else           { Kh = gen_h; VT = genT; kn2p = gn2; outp = (mode == 1) ? rep : nullptr; mask = true; }

  const int t = threadIdx.x;
  const int w = t >> 6;
  const int lane = t & 63;
  const int l15 = lane & 15;
  const int quad = lane >> 4;
  const int mh = w >> 1;
  const int nh = w & 1;
  const int i0 = ib * 32;

  if (t < 32) { qn2s[t] = gn2[i0 + t]; larr[t] = 0.f; rsqA[t] = 0.f; rsqB[t] = 0.f; }

  // Q fragments in registers: this wave's 16 rows, full K=1024.
  bf16x8 qf[32];
  {
    const unsigned short* qrow = gen_h + (size_t)(i0 + mh * 16 + l15) * DN_ + quad * 8;
#pragma unroll
    for (int ks = 0; ks < 32; ++ks) qf[ks] = *(const bf16x8*)(qrow + ks * 32);
  }

  const f32x4 fzero = {0.f, 0.f, 0.f, 0.f};
  f32x4 acc[2][16];
#pragma unroll
  for (int a = 0; a < 2; ++a)
#pragma unroll
    for (int b = 0; b < 16; ++b) acc[a][b] = fzero;
  float lacc[4] = {0.f, 0.f, 0.f, 0.f};

  // staging map: thread t covers row srow = t>>2 (0..63), 128B slice (t&3)*64 elems
  const int srow = t >> 2;
  const int scol = (t & 3) * 64;

  // initial prefetch: tile 0, chunk 0
  uint4 pre[8];
  {
    const unsigned short* kb = Kh + (size_t)srow * DN_ + scol;
#pragma unroll
    for (int u = 0; u < 8; ++u) pre[u] = *(const uint4*)(kb + u * 8);
  }

  for (int jt = 0; jt < BN_ / 64; ++jt) {
    const int j0 = jt * 64;
    const unsigned short* kbase = Kh + (size_t)(j0 + srow) * DN_ + scol;

    if (t < 64) kn2s[t] = kn2p[j0 + t];

    // ---------- phase A: S(32x64) = Q @ K_tile^T, 4 chunks of 256 d ----------
    f32x4 accs0 = fzero, accs1 = fzero;
#pragma unroll
    for (int dc = 0; dc < 4; ++dc) {
#pragma unroll
      for (int u = 0; u < 8; ++u)
        *(uint4*)(&Ks[srow][scol + u * 8]) = pre[u];
      __syncthreads();
      // prefetch: next chunk, or next tile's chunk 0
      if (dc < 3) {
#pragma unroll
        for (int u = 0; u < 8; ++u)
          pre[u] = *(const uint4*)(kbase + (dc + 1) * 256 + u * 8);
      } else if (jt + 1 < BN_ / 64) {
#pragma unroll
        for (int u = 0; u < 8; ++u)
          pre[u] = *(const uint4*)(kbase + 64 * DN_ + u * 8);
      }
#pragma unroll
      for (int ks = 0; ks < 8; ++ks) {
        bf16x8 a  = qf[dc * 8 + ks];
        bf16x8 b0 = *(const bf16x8*)(&Ks[nh * 32 + l15][ks * 32 + quad * 8]);
        bf16x8 b1 = *(const bf16x8*)(&Ks[nh * 32 + 16 + l15][ks * 32 + quad * 8]);
        accs0 = __builtin_amdgcn_mfma_f32_16x16x32_bf16(a, b0, accs0, 0, 0, 0);
        accs1 = __builtin_amdgcn_mfma_f32_16x16x32_bf16(a, b1, accs1, 0, 0, 0);
      }
      __syncthreads();
    }

    // ---------- phase B: P = exp(SHIFT - 10*dist) ----------
#pragma unroll
    for (int nt = 0; nt < 2; ++nt) {
      f32x4 av = nt ? accs1 : accs0;
      int jcol = nh * 32 + nt * 16 + l15;
      float kn = kn2s[jcol];
#pragma unroll
      for (int reg = 0; reg < 4; ++reg) {
        int r = mh * 16 + quad * 4 + reg;  // C-layout: row = quad*4 + reg
        float d2 = qn2s[r] + kn - 2.0f * av[reg];
        float dist = sqrtf(fmaxf(d2, 0.0f));
        float p = __expf(SHIFT_ - dist * INV_T);
        if (mask && (i0 + r) == (j0 + jcol)) p = 0.0f;
        lacc[reg] += p;
        Ps[r][jcol] = f2bf(p);
      }
    }
    __syncthreads();

    // ---------- phase C: O += P @ V, V B-frags direct from global VT ----------
    const unsigned short* vbase = VT + (size_t)(w * 256 + l15) * BN_ + j0 + quad * 8;
#pragma unroll
    for (int ks = 0; ks < 2; ++ks) {
      bf16x8 a0 = *(const bf16x8*)(&Ps[l15][ks * 32 + quad * 8]);
      bf16x8 a1 = *(const bf16x8*)(&Ps[16 + l15][ks * 32 + quad * 8]);
#pragma unroll
      for (int nt2 = 0; nt2 < 16; ++nt2) {
        bf16x8 bv = *(const bf16x8*)(vbase + (size_t)nt2 * 16 * BN_ + ks * 32);
        acc[0][nt2] = __builtin_amdgcn_mfma_f32_16x16x32_bf16(a0, bv, acc[0][nt2], 0, 0, 0);
        acc[1][nt2] = __builtin_amdgcn_mfma_f32_16x16x32_bf16(a1, bv, acc[1][nt2], 0, 0, 0);
      }
    }
  }

  // ---------- epilogue ----------
#pragma unroll
  for (int reg = 0; reg < 4; ++reg) {
    float v = lacc[reg];
    v += __shfl_xor(v, 1); v += __shfl_xor(v, 2);
    v += __shfl_xor(v, 4); v += __shfl_xor(v, 8);
    if (l15 == 0) atomicAdd(&larr[mh * 16 + quad * 4 + reg], v);
  }
  __syncthreads();

#pragma unroll
  for (int mt = 0; mt < 2; ++mt) {
#pragma unroll
    for (int reg = 0; reg < 4; ++reg) {
      const int r = mt * 16 + quad * 4 + reg;
      const float invl = 1.0f / larr[r];
      const size_t rowoff = (size_t)(i0 + r) * DN_ + w * 256 + l15;
      float sa = 0.f, sb = 0.f;
#pragma unroll
      for (int nt2 = 0; nt2 < 16; ++nt2) {
        int dcol = nt2 * 16;
        float o = acc[mt][nt2][reg] * invl;
        float g = genf[rowoff + dcol];
        float res = o - g;
        sa += res * res;
        if (mode == 2) {
          float av = bf2f(attr[rowoff + dcol]);
          float dr = av - res;
          sb += dr * dr;
        } else {
          outp[rowoff + dcol] = f2bf(res);
        }
      }
      sa += __shfl_xor(sa, 1); sa += __shfl_xor(sa, 2);
      sa += __shfl_xor(sa, 4); sa += __shfl_xor(sa, 8);
      if (mode == 2) {
        sb += __shfl_xor(sb, 1); sb += __shfl_xor(sb, 2);
        sb += __shfl_xor(sb, 4); sb += __shfl_xor(sb, 8);
      }
      if (l15 == 0) {
        atomicAdd(&rsqA[r], sa);
        if (mode == 2) atomicAdd(&rsqB[r], sb);
      }
    }
  }
  __syncthreads();
  if (t < 32) {
    if (mode == 0) {
      atomicAdd(&gs[2], sqrtf(rsqA[t]));
    } else if (mode == 1) {
      atomicAdd(&gs[3], sqrtf(rsqA[t]));
    } else {
      atomicAdd(&gs[3], sqrtf(rsqA[t]));
      atomicAdd(&gs[1], sqrtf(rsqB[t]));
      atomicAdd(&gs[0], rsqB[t]);
    }
  }
}

// ---------------- combine (concurrent path): drift stats from attr/rep ----------------
__global__ void combine_kernel(const unsigned short* __restrict__ attr,
                               const unsigned short* __restrict__ rep,
                               float* __restrict__ gs) {
  __shared__ float red[4];
  int t = threadIdx.x;
  int r0 = blockIdx.x * 16;
  float bs0 = 0.f, bs1 = 0.f;
  for (int rr = 0; rr < 16; ++rr) {
    size_t off = (size_t)(r0 + rr) * DN_;
    ushort4 a4 = ((const ushort4*)(attr + off))[t];
    ushort4 b4 = ((const ushort4*)(rep + off))[t];
    float d0 = bf2f(a4.x) - bf2f(b4.x);
    float d1 = bf2f(a4.y) - bf2f(b4.y);
    float d2 = bf2f(a4.z) - bf2f(b4.z);
    float d3 = bf2f(a4.w) - bf2f(b4.w);
    float s = d0 * d0 + d1 * d1 + d2 * d2 + d3 * d3;
#pragma unroll
    for (int m = 1; m < 64; m <<= 1) s += __shfl_xor(s, m);
    if ((t & 63) == 0) red[t >> 6] = s;
    __syncthreads();
    if (t == 0) {
      float rs = red[0] + red[1] + red[2] + red[3];
      bs0 += rs;
      bs1 += sqrtf(rs);
    }
    __syncthreads();
  }
  if (t == 0) { atomicAdd(&gs[0], bs0); atomicAdd(&gs[1], bs1); }
}

__global__ void finalize_kernel(const float* __restrict__ gs, float* __restrict__ out) {
  int t = threadIdx.x;
  if (t == 0) out[0] = gs[0] / (8192.0f * 1024.0f);
  if (t == 1) out[1] = gs[1] / 8192.0f;
  if (t == 2) out[2] = gs[2] / 8192.0f;
  if (t == 3) out[3] = gs[3] / 8192.0f;
}

extern "C" void kernel_launch(void* const* d_in, const int* in_sizes, int n_in,
                              void* d_out, int out_size, void* d_ws, size_t ws_size,
                              hipStream_t stream) {
  const float* gen = (const float*)d_in[0];
  const float* pos = (const float*)d_in[1];
  char* ws = (char*)d_ws;
  const size_t MB = (size_t)1 << 20;
  unsigned short* gen_h = (unsigned short*)(ws + 0 * MB);    // 16 MB
  unsigned short* pos_h = (unsigned short*)(ws + 16 * MB);   // 16 MB
  unsigned short* genT  = (unsigned short*)(ws + 32 * MB);   // 16 MB
  unsigned short* posT  = (unsigned short*)(ws + 48 * MB);   // 16 MB
  unsigned short* attr  = (unsigned short*)(ws + 64 * MB);   // 16 MB
  float* gn2 = (float*)(ws + 80 * MB);                       // 32 KB
  float* pn2 = (float*)(ws + 80 * MB + 32768);               // 32 KB
  float* gs  = (float*)(ws + 80 * MB + 65536);               // 16 B accumulators
  unsigned short* rep   = (unsigned short*)(ws + 81 * MB);   // 16 MB (concurrent path only)

  const bool concurrent = (ws_size >= (size_t)97 * MB);

  hipMemsetAsync(gs, 0, 4 * sizeof(float), stream);
  prep_kernel<<<dim3(16384), dim3(256), 0, stream>>>(gen, pos, gen_h, pos_h, gn2, pn2);
  transpose_kernel<<<dim3(4096), dim3(256), 0, stream>>>(gen, pos, genT, posT);

  if (concurrent) {
    // 512 blocks: [0,256) attraction, [256,512) repulsion -> 2 blocks/CU
    flash_kernel<<<dim3(512), dim3(256), 0, stream>>>(gen_h, pos_h, genT, posT,
                                                      gn2, pn2, gen, attr, rep, gs, -1);
    combine_kernel<<<dim3(512), dim3(256), 0, stream>>>(attr, rep, gs);
  } else {
    flash_kernel<<<dim3(256), dim3(256), 0, stream>>>(gen_h, pos_h, genT, posT,
                                                      gn2, pn2, gen, attr, nullptr, gs, 0);
    flash_kernel<<<dim3(256), dim3(256), 0, stream>>>(gen_h, pos_h, genT, posT,
                                                      gn2, pn2, gen, attr, nullptr, gs, 2);
  }
  finalize_kernel<<<dim3(1), dim3(64), 0, stream>>>(gs, (float*)d_out);
}

// Round 3
// 1551.554 us; speedup vs baseline: 3.3413x; 3.3413x over previous
//
#include <hip/hip_runtime.h>
#include <stdint.h>

#define INV_T 10.0f
#define SHIFT_ 460.0f
#define MROWS 8192
#define DDIM 1024

typedef __attribute__((ext_vector_type(8))) short bf16x8;
typedef __attribute__((ext_vector_type(4))) float f32x4;

__device__ __forceinline__ float bf2f(unsigned short u) {
  return __uint_as_float(((unsigned int)u) << 16);
}
__device__ __forceinline__ unsigned short f2bf(float f) {
  unsigned int u = __float_as_uint(f);
  return (unsigned short)((u + 0x7FFFu + ((u >> 16) & 1u)) >> 16);
}
__device__ __forceinline__ void gl2lds16(const unsigned short* g, unsigned short* l) {
  __builtin_amdgcn_global_load_lds((const __attribute__((address_space(1))) void*)g,
                                   (__attribute__((address_space(3))) void*)l, 16, 0, 0);
}

// ---------------- prep: fp32 -> bf16 cast + row sum-of-squares ----------------
__global__ void prep_kernel(const float* __restrict__ gen, const float* __restrict__ pos,
                            unsigned short* __restrict__ gen_h, unsigned short* __restrict__ pos_h,
                            float* __restrict__ gn2, float* __restrict__ pn2) {
  int b = blockIdx.x;
  const float* src; unsigned short* dst; float* n2; int row;
  if (b < MROWS) { src = gen; dst = gen_h; n2 = gn2; row = b; }
  else           { src = pos; dst = pos_h; n2 = pn2; row = b - MROWS; }
  int t = threadIdx.x;
  float4 v = ((const float4*)(src + (size_t)row * DDIM))[t];
  float ss = v.x * v.x + v.y * v.y + v.z * v.z + v.w * v.w;
  ushort4 o;
  o.x = f2bf(v.x); o.y = f2bf(v.y); o.z = f2bf(v.z); o.w = f2bf(v.w);
  ((ushort4*)(dst + (size_t)row * DDIM))[t] = o;
#pragma unroll
  for (int m = 1; m < 64; m <<= 1) ss += __shfl_xor(ss, m);
  __shared__ float red[4];
  if ((t & 63) == 0) red[t >> 6] = ss;
  __syncthreads();
  if (t == 0) n2[row] = red[0] + red[1] + red[2] + red[3];
}

// ---------------- transpose: fp32 [8192][1024] -> bf16 [1024][8192] ----------------
__global__ void transpose_kernel(const float* __restrict__ gen, const float* __restrict__ pos,
                                 unsigned short* __restrict__ genT, unsigned short* __restrict__ posT) {
  __shared__ float tile[64][65];
  int b = blockIdx.x;
  const float* src; unsigned short* dst;
  if (b < 2048) { src = gen; dst = genT; }
  else          { src = pos; dst = posT; b -= 2048; }
  int tj = b >> 4, td = b & 15;
  int t = threadIdx.x;
#pragma unroll
  for (int it = 0; it < 16; ++it) {
    int idx = it * 256 + t;
    int r = idx >> 6, c = idx & 63;
    tile[r][c] = src[(size_t)(tj * 64 + r) * DDIM + td * 64 + c];
  }
  __syncthreads();
#pragma unroll
  for (int it = 0; it < 16; ++it) {
    int idx = it * 256 + t;
    int d = idx >> 6, j = idx & 63;
    dst[(size_t)(td * 64 + d) * MROWS + tj * 64 + j] = f2bf(tile[j][d]);
  }
}

// ---------------- BT-GEMM, 128x128 tile, m97 structure ----------------
// C[128m x 128n] = A[m][k] * B'[n][k]^T over K = ksteps*64.
// EPI 0: score epilogue -> P bf16 chunk + row-sum atomics into lsum
// EPI 1: PV epilogue -> O fp32 (first ? write : accumulate)
// EPI 2: PV epilogue -> O bf16
template <int EPI>
__launch_bounds__(256, 2)
__global__ void gemm_bt(const unsigned short* __restrict__ A, long lda,
                        const unsigned short* __restrict__ B, long ldb,
                        int ksteps,
                        unsigned short* __restrict__ Pout, int pld, int j0, int domask,
                        const float* __restrict__ qn2, const float* __restrict__ kn2,
                        float* __restrict__ lsum,
                        float* __restrict__ Of, unsigned short* __restrict__ Oh, int first) {
  __shared__ __align__(16) unsigned short Al[128 * 64];
  __shared__ __align__(16) unsigned short Bl[128 * 64];
  const int t = threadIdx.x;
  const int w = t >> 6, lane = t & 63, l15 = lane & 15, quad = lane >> 4;
  const int wm = w >> 1, wn = w & 1;
  const long m0 = (long)blockIdx.x * 128;
  const long n0 = (long)blockIdx.y * 128;
  const int trow = t >> 3;
  const int tcol = (t & 7) * 8;

  f32x4 acc[4][4];
#pragma unroll
  for (int i = 0; i < 4; ++i)
#pragma unroll
    for (int j = 0; j < 4; ++j) acc[i][j] = (f32x4){0.f, 0.f, 0.f, 0.f};

  const unsigned short* Ab = A + (m0 + trow) * lda + tcol;
  const unsigned short* Bb = B + (n0 + trow) * ldb + tcol;
  unsigned short* Alw = Al + t * 8;  // lane-linear LDS dest (byte = t*16)
  unsigned short* Blw = Bl + t * 8;

  for (int ks = 0; ks < ksteps; ++ks) {
    const long ko = (long)ks * 64;
#pragma unroll
    for (int i = 0; i < 4; ++i) gl2lds16(Ab + (long)i * 32 * lda + ko, Alw + i * 2048);
#pragma unroll
    for (int i = 0; i < 4; ++i) gl2lds16(Bb + (long)i * 32 * ldb + ko, Blw + i * 2048);
    __syncthreads();
#pragma unroll
    for (int kk = 0; kk < 2; ++kk) {
      bf16x8 af[4], bfr[4];
#pragma unroll
      for (int mi = 0; mi < 4; ++mi)
        af[mi] = *(const bf16x8*)(Al + (wm * 64 + mi * 16 + l15) * 64 + kk * 32 + quad * 8);
#pragma unroll
      for (int ni = 0; ni < 4; ++ni)
        bfr[ni] = *(const bf16x8*)(Bl + (wn * 64 + ni * 16 + l15) * 64 + kk * 32 + quad * 8);
#pragma unroll
      for (int mi = 0; mi < 4; ++mi)
#pragma unroll
        for (int ni = 0; ni < 4; ++ni)
          acc[mi][ni] = __builtin_amdgcn_mfma_f32_16x16x32_bf16(af[mi], bfr[ni], acc[mi][ni], 0, 0, 0);
    }
    __syncthreads();
  }

  if (EPI == 0) {
    // score -> P = exp(SHIFT - 10*dist), row sums into lsum
#pragma unroll
    for (int mi = 0; mi < 4; ++mi) {
      float rs[4] = {0.f, 0.f, 0.f, 0.f};
#pragma unroll
      for (int ni = 0; ni < 4; ++ni) {
        int c = (int)n0 + wn * 64 + ni * 16 + l15;  // chunk-local col
        float kn = kn2[j0 + c];
#pragma unroll
        for (int reg = 0; reg < 4; ++reg) {
          long r = m0 + wm * 64 + mi * 16 + quad * 4 + reg;  // C-layout: row = quad*4+reg
          float v = acc[mi][ni][reg];
          float d2 = qn2[r] + kn - 2.0f * v;
          float p = __expf(SHIFT_ - INV_T * sqrtf(fmaxf(d2, 0.0f)));
          if (domask && (int)r == (j0 + c)) p = 0.0f;
          rs[reg] += p;
          Pout[r * (long)pld + c] = f2bf(p);
        }
      }
#pragma unroll
      for (int reg = 0; reg < 4; ++reg) {
        float v = rs[reg];
        v += __shfl_xor(v, 1); v += __shfl_xor(v, 2);
        v += __shfl_xor(v, 4); v += __shfl_xor(v, 8);
        if (l15 == 0) atomicAdd(&lsum[m0 + wm * 64 + mi * 16 + quad * 4 + reg], v);
      }
    }
  } else {
#pragma unroll
    for (int mi = 0; mi < 4; ++mi)
#pragma unroll
      for (int ni = 0; ni < 4; ++ni) {
        long c = n0 + wn * 64 + ni * 16 + l15;
#pragma unroll
        for (int reg = 0; reg < 4; ++reg) {
          long r = m0 + wm * 64 + mi * 16 + quad * 4 + reg;
          long off = r * DDIM + c;
          float v = acc[mi][ni][reg];
          if (EPI == 1) {
            Of[off] = first ? v : (Of[off] + v);
          } else {
            Oh[off] = f2bf(first ? v : (bf2f(Oh[off]) + v));
          }
        }
      }
  }
}

// ---------------- attraction epilogue: attr = O/l - gen, gs[2] += ||attr_i|| ----------------
template <bool FP32O>
__global__ void attr_epi(const float* __restrict__ Of, const unsigned short* __restrict__ Oh,
                         const float* __restrict__ lsum, const float* __restrict__ genf,
                         unsigned short* __restrict__ attr, float* __restrict__ gs) {
  __shared__ float red[4];
  int row = blockIdx.x, t = threadIdx.x;
  float invl = 1.0f / lsum[row];
  long off = (long)row * DDIM + t * 4;
  float4 g = *(const float4*)(genf + off);
  float o[4];
  if (FP32O) {
    float4 ov = *(const float4*)(Of + off);
    o[0] = ov.x; o[1] = ov.y; o[2] = ov.z; o[3] = ov.w;
  } else {
    ushort4 ov = *(const ushort4*)(Oh + off);
    o[0] = bf2f(ov.x); o[1] = bf2f(ov.y); o[2] = bf2f(ov.z); o[3] = bf2f(ov.w);
  }
  float g4[4] = {g.x, g.y, g.z, g.w};
  float a4[4], ss = 0.f;
#pragma unroll
  for (int i = 0; i < 4; ++i) { a4[i] = o[i] * invl - g4[i]; ss += a4[i] * a4[i]; }
  ushort4 st;
  st.x = f2bf(a4[0]); st.y = f2bf(a4[1]); st.z = f2bf(a4[2]); st.w = f2bf(a4[3]);
  *(ushort4*)(attr + off) = st;
#pragma unroll
  for (int m = 1; m < 64; m <<= 1) ss += __shfl_xor(ss, m);
  if ((t & 63) == 0) red[t >> 6] = ss;
  __syncthreads();
  if (t == 0) atomicAdd(&gs[2], sqrtf(red[0] + red[1] + red[2] + red[3]));
}

// ---------------- repulsion epilogue: rep = O/l - gen, drift = attr - rep ----------------
template <bool FP32O>
__global__ void rep_epi(const float* __restrict__ Of, const unsigned short* __restrict__ Oh,
                        const float* __restrict__ lsum, const float* __restrict__ genf,
                        const unsigned short* __restrict__ attr, float* __restrict__ gs) {
  __shared__ float redA[4], redB[4];
  int row = blockIdx.x, t = threadIdx.x;
  float invl = 1.0f / lsum[row];
  long off = (long)row * DDIM + t * 4;
  float4 g = *(const float4*)(genf + off);
  float o[4];
  if (FP32O) {
    float4 ov = *(const float4*)(Of + off);
    o[0] = ov.x; o[1] = ov.y; o[2] = ov.z; o[3] = ov.w;
  } else {
    ushort4 ov = *(const ushort4*)(Oh + off);
    o[0] = bf2f(ov.x); o[1] = bf2f(ov.y); o[2] = bf2f(ov.z); o[3] = bf2f(ov.w);
  }
  ushort4 av = *(const ushort4*)(attr + off);
  float g4[4] = {g.x, g.y, g.z, g.w};
  float a4[4] = {bf2f(av.x), bf2f(av.y), bf2f(av.z), bf2f(av.w)};
  float ssr = 0.f, ssd = 0.f;
#pragma unroll
  for (int i = 0; i < 4; ++i) {
    float r_ = o[i] * invl - g4[i];
    float d_ = a4[i] - r_;
    ssr += r_ * r_; ssd += d_ * d_;
  }
#pragma unroll
  for (int m = 1; m < 64; m <<= 1) { ssr += __shfl_xor(ssr, m); ssd += __shfl_xor(ssd, m); }
  if ((t & 63) == 0) { redA[t >> 6] = ssr; redB[t >> 6] = ssd; }
  __syncthreads();
  if (t == 0) {
    float R = redA[0] + redA[1] + redA[2] + redA[3];
    float D = redB[0] + redB[1] + redB[2] + redB[3];
    atomicAdd(&gs[3], sqrtf(R));
    atomicAdd(&gs[1], sqrtf(D));
    atomicAdd(&gs[0], D);
  }
}

__global__ void finalize_kernel(const float* __restrict__ gs, float* __restrict__ out) {
  int t = threadIdx.x;
  if (t == 0) out[0] = gs[0] / (8192.0f * 1024.0f);
  if (t == 1) out[1] = gs[1] / 8192.0f;
  if (t == 2) out[2] = gs[2] / 8192.0f;
  if (t == 3) out[3] = gs[3] / 8192.0f;
}

extern "C" void kernel_launch(void* const* d_in, const int* in_sizes, int n_in,
                              void* d_out, int out_size, void* d_ws, size_t ws_size,
                              hipStream_t stream) {
  const float* gen = (const float*)d_in[0];
  const float* pos = (const float*)d_in[1];
  char* ws = (char*)d_ws;
  const size_t MB = (size_t)1 << 20;
  unsigned short* gen_h = (unsigned short*)(ws + 0 * MB);    // 16 MB
  unsigned short* pos_h = (unsigned short*)(ws + 16 * MB);   // 16 MB (attr overlays after attraction)
  unsigned short* genT  = (unsigned short*)(ws + 32 * MB);   // 16 MB
  unsigned short* posT  = (unsigned short*)(ws + 48 * MB);   // 16 MB
  unsigned short* P     = (unsigned short*)(ws + 64 * MB);   // 16 or 32 MB (chunk)
  unsigned short* attr  = pos_h;                             // overlay: pos_h dead after attraction PassA

  int chunk; bool fp32o; size_t tail_off;
  float* Of = nullptr; unsigned short* Oh = nullptr;
  if (ws_size >= (size_t)132 * MB) {          // P 32MB @64, O fp32 32MB @96, tail @128
    chunk = 2048; fp32o = true;
    Of = (float*)(ws + 96 * MB); tail_off = 128 * MB;
  } else if (ws_size >= (size_t)116 * MB) {   // P 16MB @64, O fp32 32MB @80, tail @112
    chunk = 1024; fp32o = true;
    Of = (float*)(ws + 80 * MB); tail_off = 112 * MB;
  } else {                                    // P 16MB @64, O bf16 16MB @80, tail @96 (ws>=97MB known)
    chunk = 1024; fp32o = false;
    Oh = (unsigned short*)(ws + 80 * MB); tail_off = 96 * MB;
  }
  float* gn2 = (float*)(ws + tail_off);                  // 32 KB
  float* pn2 = (float*)(ws + tail_off + 32768);          // 32 KB
  float* lsum = (float*)(ws + tail_off + 65536);         // 32 KB
  float* gs = (float*)(ws + tail_off + 98304);           // 16 B

  const int nchunks = MROWS / chunk;
  const int nb = chunk / 128;      // N-blocks for PassA
  const int kb = chunk / 64;       // K-steps for PassB

  hipMemsetAsync(gs, 0, 4 * sizeof(float), stream);
  prep_kernel<<<dim3(16384), dim3(256), 0, stream>>>(gen, pos, gen_h, pos_h, gn2, pn2);
  transpose_kernel<<<dim3(4096), dim3(256), 0, stream>>>(gen, pos, genT, posT);

  // ---- attraction: K/V = pos ----
  hipMemsetAsync(lsum, 0, MROWS * sizeof(float), stream);
  for (int c = 0; c < nchunks; ++c) {
    int j0 = c * chunk;
    gemm_bt<0><<<dim3(64, nb), dim3(256), 0, stream>>>(
        gen_h, DDIM, pos_h + (long)j0 * DDIM, DDIM, 16,
        P, chunk, j0, 0, gn2, pn2, lsum, nullptr, nullptr, 0);
    if (fp32o)
      gemm_bt<1><<<dim3(64, 8), dim3(256), 0, stream>>>(
          P, chunk, posT + j0, MROWS, kb,
          nullptr, 0, 0, 0, nullptr, nullptr, nullptr, Of, nullptr, c == 0);
    else
      gemm_bt<2><<<dim3(64, 8), dim3(256), 0, stream>>>(
          P, chunk, posT + j0, MROWS, kb,
          nullptr, 0, 0, 0, nullptr, nullptr, nullptr, nullptr, Oh, c == 0);
  }
  if (fp32o) attr_epi<true><<<dim3(MROWS), dim3(256), 0, stream>>>(Of, Oh, lsum, gen, attr, gs);
  else       attr_epi<false><<<dim3(MROWS), dim3(256), 0, stream>>>(Of, Oh, lsum, gen, attr, gs);

  // ---- repulsion: K/V = gen, diagonal masked ----
  hipMemsetAsync(lsum, 0, MROWS * sizeof(float), stream);
  for (int c = 0; c < nchunks; ++c) {
    int j0 = c * chunk;
    gemm_bt<0><<<dim3(64, nb), dim3(256), 0, stream>>>(
        gen_h, DDIM, gen_h + (long)j0 * DDIM, DDIM, 16,
        P, chunk, j0, 1, gn2, gn2, lsum, nullptr, nullptr, 0);
    if (fp32o)
      gemm_bt<1><<<dim3(64, 8), dim3(256), 0, stream>>>(
          P, chunk, genT + j0, MROWS, kb,
          nullptr, 0, 0, 0, nullptr, nullptr, nullptr, Of, nullptr, c == 0);
    else
      gemm_bt<2><<<dim3(64, 8), dim3(256), 0, stream>>>(
          P, chunk, genT + j0, MROWS, kb,
          nullptr, 0, 0, 0, nullptr, nullptr, nullptr, nullptr, Oh, c == 0);
  }
  if (fp32o) rep_epi<true><<<dim3(MROWS), dim3(256), 0, stream>>>(Of, Oh, lsum, gen, attr, gs);
  else       rep_epi<false><<<dim3(MROWS), dim3(256), 0, stream>>>(Of, Oh, lsum, gen, attr, gs);

  finalize_kernel<<<dim3(1), dim3(64), 0, stream>>>(gs, (float*)d_out);
}

// Round 4
// 1161.630 us; speedup vs baseline: 4.4629x; 1.3357x over previous
//
#include <hip/hip_runtime.h>
#include <stdint.h>

#define INV_T 10.0f
#define SHIFT_ 460.0f
#define MROWS 8192
#define DDIM 1024

typedef __attribute__((ext_vector_type(8))) short bf16x8;
typedef __attribute__((ext_vector_type(4))) float f32x4;

__device__ __forceinline__ float bf2f(unsigned short u) {
  return __uint_as_float(((unsigned int)u) << 16);
}
__device__ __forceinline__ unsigned short f2bf(float f) {
  unsigned int u = __float_as_uint(f);
  return (unsigned short)((u + 0x7FFFu + ((u >> 16) & 1u)) >> 16);
}
__device__ __forceinline__ void gl2lds16(const unsigned short* g, unsigned short* l) {
  __builtin_amdgcn_global_load_lds((const __attribute__((address_space(1))) void*)g,
                                   (__attribute__((address_space(3))) void*)l, 16, 0, 0);
}

// ---------------- prep: fp32 -> bf16 cast + row sum-of-squares ----------------
__global__ void prep_kernel(const float* __restrict__ gen, const float* __restrict__ pos,
                            unsigned short* __restrict__ gen_h, unsigned short* __restrict__ pos_h,
                            float* __restrict__ gn2, float* __restrict__ pn2) {
  int b = blockIdx.x;
  const float* src; unsigned short* dst; float* n2; int row;
  if (b < MROWS) { src = gen; dst = gen_h; n2 = gn2; row = b; }
  else           { src = pos; dst = pos_h; n2 = pn2; row = b - MROWS; }
  int t = threadIdx.x;
  float4 v = ((const float4*)(src + (size_t)row * DDIM))[t];
  float ss = v.x * v.x + v.y * v.y + v.z * v.z + v.w * v.w;
  ushort4 o;
  o.x = f2bf(v.x); o.y = f2bf(v.y); o.z = f2bf(v.z); o.w = f2bf(v.w);
  ((ushort4*)(dst + (size_t)row * DDIM))[t] = o;
#pragma unroll
  for (int m = 1; m < 64; m <<= 1) ss += __shfl_xor(ss, m);
  __shared__ float red[4];
  if ((t & 63) == 0) red[t >> 6] = ss;
  __syncthreads();
  if (t == 0) n2[row] = red[0] + red[1] + red[2] + red[3];
}

// ---------------- transpose: fp32 [8192][1024] -> bf16 [1024][8192] ----------------
__global__ void transpose_kernel(const float* __restrict__ gen, const float* __restrict__ pos,
                                 unsigned short* __restrict__ genT, unsigned short* __restrict__ posT) {
  __shared__ float tile[64][65];
  int b = blockIdx.x;
  const float* src; unsigned short* dst;
  if (b < 2048) { src = gen; dst = genT; }
  else          { src = pos; dst = posT; b -= 2048; }
  int tj = b >> 4, td = b & 15;
  int t = threadIdx.x;
#pragma unroll
  for (int it = 0; it < 16; ++it) {
    int idx = it * 256 + t;
    int r = idx >> 6, c = idx & 63;
    tile[r][c] = src[(size_t)(tj * 64 + r) * DDIM + td * 64 + c];
  }
  __syncthreads();
#pragma unroll
  for (int it = 0; it < 16; ++it) {
    int idx = it * 256 + t;
    int d = idx >> 6, j = idx & 63;
    dst[(size_t)(td * 64 + d) * MROWS + tj * 64 + j] = f2bf(tile[j][d]);
  }
}

// ---------------- BT-GEMM, 128x128 tile, m97 structure ----------------
// C[128m x 128n] = A[m][k] * B'[n][k]^T over K = ksteps*64.
// EPI 0: score epilogue -> P bf16 chunk + row-sum atomics into lsum
// EPI 1: PV epilogue -> O fp32 (first ? write : accumulate)
// EPI 2: PV epilogue -> O bf16
template <int EPI>
__launch_bounds__(256, 2)
__global__ void gemm_bt(const unsigned short* __restrict__ A, long lda,
                        const unsigned short* __restrict__ B, long ldb,
                        int ksteps,
                        unsigned short* __restrict__ Pout, int pld, int j0, int domask,
                        const float* __restrict__ qn2, const float* __restrict__ kn2,
                        float* __restrict__ lsum,
                        float* __restrict__ Of, unsigned short* __restrict__ Oh, int first) {
  __shared__ __align__(16) unsigned short Al[128 * 64];
  __shared__ __align__(16) unsigned short Bl[128 * 64];
  const int t = threadIdx.x;
  const int w = t >> 6, lane = t & 63, l15 = lane & 15, quad = lane >> 4;
  const int wm = w >> 1, wn = w & 1;
  const long m0 = (long)blockIdx.x * 128;
  const long n0 = (long)blockIdx.y * 128;
  const int trow = t >> 3;
  const int tcol = (t & 7) * 8;

  f32x4 acc[4][4];
#pragma unroll
  for (int i = 0; i < 4; ++i)
#pragma unroll
    for (int j = 0; j < 4; ++j) acc[i][j] = (f32x4){0.f, 0.f, 0.f, 0.f};

  const unsigned short* Ab = A + (m0 + trow) * lda + tcol;
  const unsigned short* Bb = B + (n0 + trow) * ldb + tcol;
  unsigned short* Alw = Al + t * 8;  // lane-linear LDS dest (byte = t*16)
  unsigned short* Blw = Bl + t * 8;

  for (int ks = 0; ks < ksteps; ++ks) {
    const long ko = (long)ks * 64;
#pragma unroll
    for (int i = 0; i < 4; ++i) gl2lds16(Ab + (long)i * 32 * lda + ko, Alw + i * 2048);
#pragma unroll
    for (int i = 0; i < 4; ++i) gl2lds16(Bb + (long)i * 32 * ldb + ko, Blw + i * 2048);
    __syncthreads();
#pragma unroll
    for (int kk = 0; kk < 2; ++kk) {
      bf16x8 af[4], bfr[4];
#pragma unroll
      for (int mi = 0; mi < 4; ++mi)
        af[mi] = *(const bf16x8*)(Al + (wm * 64 + mi * 16 + l15) * 64 + kk * 32 + quad * 8);
#pragma unroll
      for (int ni = 0; ni < 4; ++ni)
        bfr[ni] = *(const bf16x8*)(Bl + (wn * 64 + ni * 16 + l15) * 64 + kk * 32 + quad * 8);
#pragma unroll
      for (int mi = 0; mi < 4; ++mi)
#pragma unroll
        for (int ni = 0; ni < 4; ++ni)
          acc[mi][ni] = __builtin_amdgcn_mfma_f32_16x16x32_bf16(af[mi], bfr[ni], acc[mi][ni], 0, 0, 0);
    }
    __syncthreads();
  }

  if (EPI == 0) {
    // score -> P = exp(SHIFT - 10*dist), row sums into lsum
#pragma unroll
    for (int mi = 0; mi < 4; ++mi) {
      float rs[4] = {0.f, 0.f, 0.f, 0.f};
#pragma unroll
      for (int ni = 0; ni < 4; ++ni) {
        int c = (int)n0 + wn * 64 + ni * 16 + l15;  // chunk-local col
        float kn = kn2[j0 + c];
#pragma unroll
        for (int reg = 0; reg < 4; ++reg) {
          long r = m0 + wm * 64 + mi * 16 + quad * 4 + reg;  // C-layout: row = quad*4+reg
          float v = acc[mi][ni][reg];
          float d2 = qn2[r] + kn - 2.0f * v;
          float p = __expf(SHIFT_ - INV_T * sqrtf(fmaxf(d2, 0.0f)));
          if (domask && (int)r == (j0 + c)) p = 0.0f;
          rs[reg] += p;
          Pout[r * (long)pld + c] = f2bf(p);
        }
      }
#pragma unroll
      for (int reg = 0; reg < 4; ++reg) {
        float v = rs[reg];
        v += __shfl_xor(v, 1); v += __shfl_xor(v, 2);
        v += __shfl_xor(v, 4); v += __shfl_xor(v, 8);
        if (l15 == 0) atomicAdd(&lsum[m0 + wm * 64 + mi * 16 + quad * 4 + reg], v);
      }
    }
  } else {
#pragma unroll
    for (int mi = 0; mi < 4; ++mi)
#pragma unroll
      for (int ni = 0; ni < 4; ++ni) {
        long c = n0 + wn * 64 + ni * 16 + l15;
#pragma unroll
        for (int reg = 0; reg < 4; ++reg) {
          long r = m0 + wm * 64 + mi * 16 + quad * 4 + reg;
          long off = r * DDIM + c;
          float v = acc[mi][ni][reg];
          if (EPI == 1) {
            Of[off] = first ? v : (Of[off] + v);
          } else {
            Oh[off] = f2bf(first ? v : (bf2f(Oh[off]) + v));
          }
        }
      }
  }
}

// ---------------- epilogues: 256 blocks x 32 rows; wave owns 8 rows; 3 atomics/block ----------------
// MODE 0: attr = O/l - gen, writes attr bf16, gs[2] += sum||attr_i||
// MODE 1: rep  = O/l - gen, drift = attr - rep; gs[0]+=sum drift^2, gs[1]+=sum||drift||, gs[3]+=sum||rep||
template <bool FP32O, int MODE>
__global__ void epi_kernel(const float* __restrict__ Of, const unsigned short* __restrict__ Oh,
                           const float* __restrict__ lsum, const float* __restrict__ genf,
                           unsigned short* __restrict__ attr, float* __restrict__ gs) {
  __shared__ float wsA[4], wsB[4], wsC[4];
  const int t = threadIdx.x;
  const int w = t >> 6;
  const int lane = t & 63;
  float accA = 0.f, accB = 0.f, accC = 0.f;

  for (int i = 0; i < 8; ++i) {
    const int row = blockIdx.x * 32 + w * 8 + i;
    const float invl = 1.0f / lsum[row];
    float ss1 = 0.f, ss2 = 0.f;
#pragma unroll
    for (int u = 0; u < 4; ++u) {
      const long off = (long)row * DDIM + u * 256 + lane * 4;
      float4 g = *(const float4*)(genf + off);
      float o[4];
      if (FP32O) {
        float4 ov = *(const float4*)(Of + off);
        o[0] = ov.x; o[1] = ov.y; o[2] = ov.z; o[3] = ov.w;
      } else {
        ushort4 ov = *(const ushort4*)(Oh + off);
        o[0] = bf2f(ov.x); o[1] = bf2f(ov.y); o[2] = bf2f(ov.z); o[3] = bf2f(ov.w);
      }
      float g4[4] = {g.x, g.y, g.z, g.w};
      if (MODE == 0) {
        float r4[4];
#pragma unroll
        for (int e = 0; e < 4; ++e) { r4[e] = o[e] * invl - g4[e]; ss1 += r4[e] * r4[e]; }
        ushort4 st;
        st.x = f2bf(r4[0]); st.y = f2bf(r4[1]); st.z = f2bf(r4[2]); st.w = f2bf(r4[3]);
        *(ushort4*)(attr + off) = st;
      } else {
        ushort4 av = *(const ushort4*)(attr + off);
        float a4[4] = {bf2f(av.x), bf2f(av.y), bf2f(av.z), bf2f(av.w)};
#pragma unroll
        for (int e = 0; e < 4; ++e) {
          float r_ = o[e] * invl - g4[e];
          float d_ = a4[e] - r_;
          ss1 += r_ * r_; ss2 += d_ * d_;
        }
      }
    }
#pragma unroll
    for (int m = 1; m < 64; m <<= 1) {
      ss1 += __shfl_xor(ss1, m);
      if (MODE == 1) ss2 += __shfl_xor(ss2, m);
    }
    accA += sqrtf(ss1);           // sum ||attr|| or sum ||rep||
    if (MODE == 1) { accB += sqrtf(ss2); accC += ss2; }  // sum ||drift||, sum drift^2
  }
  if (lane == 0) { wsA[w] = accA; wsB[w] = accB; wsC[w] = accC; }
  __syncthreads();
  if (t == 0) {
    float A = wsA[0] + wsA[1] + wsA[2] + wsA[3];
    if (MODE == 0) {
      atomicAdd(&gs[2], A);
    } else {
      float B = wsB[0] + wsB[1] + wsB[2] + wsB[3];
      float C = wsC[0] + wsC[1] + wsC[2] + wsC[3];
      atomicAdd(&gs[3], A);
      atomicAdd(&gs[1], B);
      atomicAdd(&gs[0], C);
    }
  }
}

__global__ void finalize_kernel(const float* __restrict__ gs, float* __restrict__ out) {
  int t = threadIdx.x;
  if (t == 0) out[0] = gs[0] / (8192.0f * 1024.0f);
  if (t == 1) out[1] = gs[1] / 8192.0f;
  if (t == 2) out[2] = gs[2] / 8192.0f;
  if (t == 3) out[3] = gs[3] / 8192.0f;
}

extern "C" void kernel_launch(void* const* d_in, const int* in_sizes, int n_in,
                              void* d_out, int out_size, void* d_ws, size_t ws_size,
                              hipStream_t stream) {
  const float* gen = (const float*)d_in[0];
  const float* pos = (const float*)d_in[1];
  char* ws = (char*)d_ws;
  const size_t MB = (size_t)1 << 20;
  unsigned short* gen_h = (unsigned short*)(ws + 0 * MB);    // 16 MB
  unsigned short* pos_h = (unsigned short*)(ws + 16 * MB);   // 16 MB (attr overlays after attraction)
  unsigned short* genT  = (unsigned short*)(ws + 32 * MB);   // 16 MB
  unsigned short* posT  = (unsigned short*)(ws + 48 * MB);   // 16 MB
  unsigned short* P     = (unsigned short*)(ws + 64 * MB);   // 16 or 32 MB (chunk)
  unsigned short* attr  = pos_h;                             // overlay: pos_h dead after attraction PassA

  int chunk; bool fp32o; size_t tail_off;
  float* Of = nullptr; unsigned short* Oh = nullptr;
  if (ws_size >= (size_t)132 * MB) {          // P 32MB @64, O fp32 32MB @96, tail @128
    chunk = 2048; fp32o = true;
    Of = (float*)(ws + 96 * MB); tail_off = 128 * MB;
  } else if (ws_size >= (size_t)116 * MB) {   // P 16MB @64, O fp32 32MB @80, tail @112
    chunk = 1024; fp32o = true;
    Of = (float*)(ws + 80 * MB); tail_off = 112 * MB;
  } else {                                    // P 16MB @64, O bf16 16MB @80, tail @96 (ws>=97MB known)
    chunk = 1024; fp32o = false;
    Oh = (unsigned short*)(ws + 80 * MB); tail_off = 96 * MB;
  }
  float* gn2 = (float*)(ws + tail_off);                  // 32 KB
  float* pn2 = (float*)(ws + tail_off + 32768);          // 32 KB
  float* lsum = (float*)(ws + tail_off + 65536);         // 32 KB
  float* gs = (float*)(ws + tail_off + 98304);           // 16 B

  const int nchunks = MROWS / chunk;
  const int nb = chunk / 128;      // N-blocks for PassA
  const int kb = chunk / 64;       // K-steps for PassB

  hipMemsetAsync(gs, 0, 4 * sizeof(float), stream);
  prep_kernel<<<dim3(16384), dim3(256), 0, stream>>>(gen, pos, gen_h, pos_h, gn2, pn2);
  transpose_kernel<<<dim3(4096), dim3(256), 0, stream>>>(gen, pos, genT, posT);

  // ---- attraction: K/V = pos ----
  hipMemsetAsync(lsum, 0, MROWS * sizeof(float), stream);
  for (int c = 0; c < nchunks; ++c) {
    int j0 = c * chunk;
    gemm_bt<0><<<dim3(64, nb), dim3(256), 0, stream>>>(
        gen_h, DDIM, pos_h + (long)j0 * DDIM, DDIM, 16,
        P, chunk, j0, 0, gn2, pn2, lsum, nullptr, nullptr, 0);
    if (fp32o)
      gemm_bt<1><<<dim3(64, 8), dim3(256), 0, stream>>>(
          P, chunk, posT + j0, MROWS, kb,
          nullptr, 0, 0, 0, nullptr, nullptr, nullptr, Of, nullptr, c == 0);
    else
      gemm_bt<2><<<dim3(64, 8), dim3(256), 0, stream>>>(
          P, chunk, posT + j0, MROWS, kb,
          nullptr, 0, 0, 0, nullptr, nullptr, nullptr, nullptr, Oh, c == 0);
  }
  if (fp32o) epi_kernel<true, 0><<<dim3(256), dim3(256), 0, stream>>>(Of, Oh, lsum, gen, attr, gs);
  else       epi_kernel<false, 0><<<dim3(256), dim3(256), 0, stream>>>(Of, Oh, lsum, gen, attr, gs);

  // ---- repulsion: K/V = gen, diagonal masked ----
  hipMemsetAsync(lsum, 0, MROWS * sizeof(float), stream);
  for (int c = 0; c < nchunks; ++c) {
    int j0 = c * chunk;
    gemm_bt<0><<<dim3(64, nb), dim3(256), 0, stream>>>(
        gen_h, DDIM, gen_h + (long)j0 * DDIM, DDIM, 16,
        P, chunk, j0, 1, gn2, gn2, lsum, nullptr, nullptr, 0);
    if (fp32o)
      gemm_bt<1><<<dim3(64, 8), dim3(256), 0, stream>>>(
          P, chunk, genT + j0, MROWS, kb,
          nullptr, 0, 0, 0, nullptr, nullptr, nullptr, Of, nullptr, c == 0);
    else
      gemm_bt<2><<<dim3(64, 8), dim3(256), 0, stream>>>(
          P, chunk, genT + j0, MROWS, kb,
          nullptr, 0, 0, 0, nullptr, nullptr, nullptr, nullptr, Oh, c == 0);
  }
  if (fp32o) epi_kernel<true, 1><<<dim3(256), dim3(256), 0, stream>>>(Of, Oh, lsum, gen, attr, gs);
  else       epi_kernel<false, 1><<<dim3(256), dim3(256), 0, stream>>>(Of, Oh, lsum, gen, attr, gs);

  finalize_kernel<<<dim3(1), dim3(64), 0, stream>>>(gs, (float*)d_out);
}

// Round 5
// 943.299 us; speedup vs baseline: 5.4959x; 1.2315x over previous
//
#include <hip/hip_runtime.h>
#include <stdint.h>

#define INV_T 10.0f
#define SHIFT_ 460.0f
#define MROWS 8192
#define DDIM 1024
#define CHUNK 1024

typedef __attribute__((ext_vector_type(8))) short bf16x8;
typedef __attribute__((ext_vector_type(4))) float f32x4;

__device__ __forceinline__ float bf2f(unsigned short u) {
  return __uint_as_float(((unsigned int)u) << 16);
}
__device__ __forceinline__ unsigned short f2bf(float f) {
  unsigned int u = __float_as_uint(f);
  return (unsigned short)((u + 0x7FFFu + ((u >> 16) & 1u)) >> 16);
}
__device__ __forceinline__ void gl2lds16(const unsigned short* g, unsigned short* l) {
  __builtin_amdgcn_global_load_lds((const __attribute__((address_space(1))) void*)g,
                                   (__attribute__((address_space(3))) void*)l, 16, 0, 0);
}

// ---------------- prep: fp32 -> bf16 cast + row sum-of-squares ----------------
__global__ void prep_kernel(const float* __restrict__ gen, const float* __restrict__ pos,
                            unsigned short* __restrict__ gen_h, unsigned short* __restrict__ pos_h,
                            float* __restrict__ gn2, float* __restrict__ pn2) {
  int b = blockIdx.x;
  const float* src; unsigned short* dst; float* n2; int row;
  if (b < MROWS) { src = gen; dst = gen_h; n2 = gn2; row = b; }
  else           { src = pos; dst = pos_h; n2 = pn2; row = b - MROWS; }
  int t = threadIdx.x;
  float4 v = ((const float4*)(src + (size_t)row * DDIM))[t];
  float ss = v.x * v.x + v.y * v.y + v.z * v.z + v.w * v.w;
  ushort4 o;
  o.x = f2bf(v.x); o.y = f2bf(v.y); o.z = f2bf(v.z); o.w = f2bf(v.w);
  ((ushort4*)(dst + (size_t)row * DDIM))[t] = o;
#pragma unroll
  for (int m = 1; m < 64; m <<= 1) ss += __shfl_xor(ss, m);
  __shared__ float red[4];
  if ((t & 63) == 0) red[t >> 6] = ss;
  __syncthreads();
  if (t == 0) n2[row] = red[0] + red[1] + red[2] + red[3];
}

// ---------------- transpose: fp32 [8192][1024] -> bf16 [1024][8192] ----------------
__global__ void transpose_kernel(const float* __restrict__ gen, const float* __restrict__ pos,
                                 unsigned short* __restrict__ genT, unsigned short* __restrict__ posT) {
  __shared__ float tile[64][65];
  int b = blockIdx.x;
  const float* src; unsigned short* dst;
  if (b < 2048) { src = gen; dst = genT; }
  else          { src = pos; dst = posT; b -= 2048; }
  int tj = b >> 4, td = b & 15;
  int t = threadIdx.x;
#pragma unroll
  for (int it = 0; it < 16; ++it) {
    int idx = it * 256 + t;
    int r = idx >> 6, c = idx & 63;
    tile[r][c] = src[(size_t)(tj * 64 + r) * DDIM + td * 64 + c];
  }
  __syncthreads();
#pragma unroll
  for (int it = 0; it < 16; ++it) {
    int idx = it * 256 + t;
    int d = idx >> 6, j = idx & 63;
    dst[(size_t)(td * 64 + d) * MROWS + tj * 64 + j] = f2bf(tile[j][d]);
  }
}

// ---------------- BT-GEMM, 128x128 tile, XOR-swizzled LDS, dual-stream via blockIdx.z ----------------
// z=0: attraction stream (B0/P0/kn2a/lsum0/O0), z=1: repulsion stream (masked diag).
// EPI 0: score epilogue -> P bf16 chunk + row-sum atomics into lsum
// EPI 1: PV epilogue -> O bf16 (first ? write : accumulate)
template <int EPI>
__launch_bounds__(256, 2)
__global__ void gemm_bt(const unsigned short* __restrict__ A0, const unsigned short* __restrict__ A1,
                        long lda,
                        const unsigned short* __restrict__ B0, const unsigned short* __restrict__ B1,
                        long ldb, int ksteps,
                        unsigned short* __restrict__ P0, unsigned short* __restrict__ P1,
                        int pld, int j0,
                        const float* __restrict__ qn2,
                        const float* __restrict__ kn2a, const float* __restrict__ kn2b,
                        float* __restrict__ lsum0, float* __restrict__ lsum1,
                        unsigned short* __restrict__ O0, unsigned short* __restrict__ O1,
                        int first) {
  __shared__ __align__(16) unsigned short Al[128 * 64];
  __shared__ __align__(16) unsigned short Bl[128 * 64];
  const int z = blockIdx.z;
  const unsigned short* A = z ? A1 : A0;
  const unsigned short* B = z ? B1 : B0;
  const int t = threadIdx.x;
  const int w = t >> 6, lane = t & 63, l15 = lane & 15, quad = lane >> 4;
  const int wm = w >> 1, wn = w & 1;
  const long m0 = (long)blockIdx.x * 128;
  const long n0 = (long)blockIdx.y * 128;
  const int trow = t >> 3;                       // 0..31
  const int tcol = (((t & 7) ^ (trow & 7)) * 8); // XOR-swizzled global 16B-unit

  f32x4 acc[4][4];
#pragma unroll
  for (int i = 0; i < 4; ++i)
#pragma unroll
    for (int j = 0; j < 4; ++j) acc[i][j] = (f32x4){0.f, 0.f, 0.f, 0.f};

  const unsigned short* Ab = A + (m0 + trow) * lda + tcol;
  const unsigned short* Bb = B + (n0 + trow) * ldb + tcol;
  unsigned short* Alw = Al + t * 8;  // lane-linear LDS dest (byte = t*16)
  unsigned short* Blw = Bl + t * 8;
  const int ue = (quad ^ (l15 & 7)) * 8;  // swizzled read unit (elems)

  for (int ks = 0; ks < ksteps; ++ks) {
    const long ko = (long)ks * 64;
#pragma unroll
    for (int i = 0; i < 4; ++i) gl2lds16(Ab + (long)i * 32 * lda + ko, Alw + i * 2048);
#pragma unroll
    for (int i = 0; i < 4; ++i) gl2lds16(Bb + (long)i * 32 * ldb + ko, Blw + i * 2048);
    __syncthreads();
#pragma unroll
    for (int kk = 0; kk < 2; ++kk) {
      const int uo = ue ^ (kk * 32);
      bf16x8 af[4], bfr[4];
#pragma unroll
      for (int mi = 0; mi < 4; ++mi)
        af[mi] = *(const bf16x8*)(Al + (wm * 64 + mi * 16 + l15) * 64 + uo);
#pragma unroll
      for (int ni = 0; ni < 4; ++ni)
        bfr[ni] = *(const bf16x8*)(Bl + (wn * 64 + ni * 16 + l15) * 64 + uo);
#pragma unroll
      for (int mi = 0; mi < 4; ++mi)
#pragma unroll
        for (int ni = 0; ni < 4; ++ni)
          acc[mi][ni] = __builtin_amdgcn_mfma_f32_16x16x32_bf16(af[mi], bfr[ni], acc[mi][ni], 0, 0, 0);
    }
    __syncthreads();
  }

  if (EPI == 0) {
    unsigned short* Pout = z ? P1 : P0;
    const float* kn2 = z ? kn2b : kn2a;
    float* lsum = z ? lsum1 : lsum0;
#pragma unroll
    for (int mi = 0; mi < 4; ++mi) {
      float rs[4] = {0.f, 0.f, 0.f, 0.f};
#pragma unroll
      for (int ni = 0; ni < 4; ++ni) {
        int c = (int)n0 + wn * 64 + ni * 16 + l15;  // chunk-local col
        float kn = kn2[j0 + c];
#pragma unroll
        for (int reg = 0; reg < 4; ++reg) {
          long r = m0 + wm * 64 + mi * 16 + quad * 4 + reg;  // C-layout: row = quad*4+reg
          float v = acc[mi][ni][reg];
          float d2 = qn2[r] + kn - 2.0f * v;
          float p = __expf(SHIFT_ - INV_T * sqrtf(fmaxf(d2, 0.0f)));
          if (z && (int)r == (j0 + c)) p = 0.0f;
          rs[reg] += p;
          Pout[r * (long)pld + c] = f2bf(p);
        }
      }
#pragma unroll
      for (int reg = 0; reg < 4; ++reg) {
        float v = rs[reg];
        v += __shfl_xor(v, 1); v += __shfl_xor(v, 2);
        v += __shfl_xor(v, 4); v += __shfl_xor(v, 8);
        if (l15 == 0) atomicAdd(&lsum[m0 + wm * 64 + mi * 16 + quad * 4 + reg], v);
      }
    }
  } else {
    unsigned short* Oh = z ? O1 : O0;
#pragma unroll
    for (int mi = 0; mi < 4; ++mi)
#pragma unroll
      for (int ni = 0; ni < 4; ++ni) {
        long c = n0 + wn * 64 + ni * 16 + l15;
#pragma unroll
        for (int reg = 0; reg < 4; ++reg) {
          long r = m0 + wm * 64 + mi * 16 + quad * 4 + reg;
          long off = r * DDIM + c;
          float v = acc[mi][ni][reg];
          Oh[off] = f2bf(first ? v : (bf2f(Oh[off]) + v));
        }
      }
  }
}

// ---------------- merged epilogue: all four stats in one pass; 4 atomics/block ----------------
__global__ void epi_kernel(const unsigned short* __restrict__ OA, const unsigned short* __restrict__ OR_,
                           const float* __restrict__ lsumA, const float* __restrict__ lsumR,
                           const float* __restrict__ genf, float* __restrict__ gs) {
  __shared__ float wsL[4], wsD[4], wsA[4], wsR[4];
  const int t = threadIdx.x;
  const int w = t >> 6;
  const int lane = t & 63;
  float accL = 0.f, accD = 0.f, accA = 0.f, accR = 0.f;

  for (int i = 0; i < 8; ++i) {
    const int row = blockIdx.x * 32 + w * 8 + i;
    const float invlA = 1.0f / lsumA[row];
    const float invlR = 1.0f / lsumR[row];
    float ssA = 0.f, ssR = 0.f, ssD = 0.f;
#pragma unroll
    for (int u = 0; u < 4; ++u) {
      const long off = (long)row * DDIM + u * 256 + lane * 4;
      float4 g = *(const float4*)(genf + off);
      ushort4 oa = *(const ushort4*)(OA + off);
      ushort4 orr = *(const ushort4*)(OR_ + off);
      float g4[4] = {g.x, g.y, g.z, g.w};
      float a4[4] = {bf2f(oa.x), bf2f(oa.y), bf2f(oa.z), bf2f(oa.w)};
      float r4[4] = {bf2f(orr.x), bf2f(orr.y), bf2f(orr.z), bf2f(orr.w)};
#pragma unroll
      for (int e = 0; e < 4; ++e) {
        float a_ = a4[e] * invlA - g4[e];
        float r_ = r4[e] * invlR - g4[e];
        float d_ = a_ - r_;
        ssA += a_ * a_; ssR += r_ * r_; ssD += d_ * d_;
      }
    }
#pragma unroll
    for (int m = 1; m < 64; m <<= 1) {
      ssA += __shfl_xor(ssA, m);
      ssR += __shfl_xor(ssR, m);
      ssD += __shfl_xor(ssD, m);
    }
    accA += sqrtf(ssA); accR += sqrtf(ssR); accD += sqrtf(ssD); accL += ssD;
  }
  if (lane == 0) { wsL[w] = accL; wsD[w] = accD; wsA[w] = accA; wsR[w] = accR; }
  __syncthreads();
  if (t == 0) {
    atomicAdd(&gs[0], wsL[0] + wsL[1] + wsL[2] + wsL[3]);
    atomicAdd(&gs[1], wsD[0] + wsD[1] + wsD[2] + wsD[3]);
    atomicAdd(&gs[2], wsA[0] + wsA[1] + wsA[2] + wsA[3]);
    atomicAdd(&gs[3], wsR[0] + wsR[1] + wsR[2] + wsR[3]);
  }
}

__global__ void finalize_kernel(const float* __restrict__ gs, float* __restrict__ out) {
  int t = threadIdx.x;
  if (t == 0) out[0] = gs[0] / (8192.0f * 1024.0f);
  if (t == 1) out[1] = gs[1] / 8192.0f;
  if (t == 2) out[2] = gs[2] / 8192.0f;
  if (t == 3) out[3] = gs[3] / 8192.0f;
}

extern "C" void kernel_launch(void* const* d_in, const int* in_sizes, int n_in,
                              void* d_out, int out_size, void* d_ws, size_t ws_size,
                              hipStream_t stream) {
  const float* gen = (const float*)d_in[0];
  const float* pos = (const float*)d_in[1];
  char* ws = (char*)d_ws;
  const size_t MB = (size_t)1 << 20;
  unsigned short* gen_h = (unsigned short*)(ws + 0 * MB);    // 16 MB
  unsigned short* pos_h = (unsigned short*)(ws + 16 * MB);   // 16 MB
  unsigned short* genT  = (unsigned short*)(ws + 32 * MB);   // 16 MB
  unsigned short* posT  = (unsigned short*)(ws + 48 * MB);   // 16 MB
  unsigned short* Pa    = (unsigned short*)(ws + 64 * MB);   // 16 MB  (attr P chunk)
  unsigned short* Pr    = (unsigned short*)(ws + 80 * MB);   // 16 MB  (rep P chunk)
  unsigned short* OhA   = (unsigned short*)(ws + 96 * MB);   // 16 MB  (attr O, bf16)
  unsigned short* OhR   = (unsigned short*)(ws + 112 * MB);  // 16 MB  (rep O, bf16)
  float* gn2   = (float*)(ws + 128 * MB);                    // 32 KB
  float* pn2   = (float*)(ws + 128 * MB + 32768);            // 32 KB
  float* lsumA = (float*)(ws + 128 * MB + 65536);            // 32 KB
  float* lsumR = (float*)(ws + 128 * MB + 98304);            // 32 KB
  float* gs    = (float*)(ws + 128 * MB + 131072);           // 16 B

  hipMemsetAsync(gs, 0, 4 * sizeof(float), stream);
  hipMemsetAsync(lsumA, 0, 2 * MROWS * sizeof(float), stream);  // lsumA + lsumR contiguous
  prep_kernel<<<dim3(16384), dim3(256), 0, stream>>>(gen, pos, gen_h, pos_h, gn2, pn2);
  transpose_kernel<<<dim3(4096), dim3(256), 0, stream>>>(gen, pos, genT, posT);

  const int nchunks = MROWS / CHUNK;
  for (int c = 0; c < nchunks; ++c) {
    const int j0 = c * CHUNK;
    // PassA: S-chunk for both streams; A = gen_h for both, B = pos_h / gen_h rows [j0, j0+CHUNK)
    gemm_bt<0><<<dim3(64, CHUNK / 128, 2), dim3(256), 0, stream>>>(
        gen_h, gen_h, DDIM,
        pos_h + (long)j0 * DDIM, gen_h + (long)j0 * DDIM, DDIM, DDIM / 64,
        Pa, Pr, CHUNK, j0, gn2, pn2, gn2, lsumA, lsumR, nullptr, nullptr, 0);
    // PassB: O += P-chunk @ V; A = P chunks, B = transposed V slabs
    gemm_bt<1><<<dim3(64, DDIM / 128, 2), dim3(256), 0, stream>>>(
        Pa, Pr, CHUNK,
        posT + j0, genT + j0, MROWS, CHUNK / 64,
        nullptr, nullptr, 0, 0, nullptr, nullptr, nullptr, nullptr, nullptr,
        OhA, OhR, c == 0);
  }

  epi_kernel<<<dim3(256), dim3(256), 0, stream>>>(OhA, OhR, lsumA, lsumR, gen, gs);
  finalize_kernel<<<dim3(1), dim3(64), 0, stream>>>(gs, (float*)d_out);
}